// Round 1
// baseline (1170.182 us; speedup 1.0000x reference)
//
#include <hip/hip_runtime.h>
#include <hip/hip_bf16.h>

#define B_ 8
#define T_ 8192
#define M_ (B_ * T_)          // 65536 rows
#define IDIM 256
#define HDIM 1024
#define ODIM 256
#define CDIM 128
#define OUT_OFF ((size_t)M_ * ODIM)   // start of mask_new region in d_out

typedef __attribute__((ext_vector_type(4))) float floatx4;
typedef __attribute__((ext_vector_type(8))) short shortx8;

// ---------------------------------------------------------------------------
// K0: WdT[n][k] = bf16(W_dec_sel[k][n])  (transposed so MFMA B-frag reads are
// contiguous-k vector loads)
// ---------------------------------------------------------------------------
__global__ __launch_bounds__(256) void k0_convw(const float* __restrict__ Wself,
                                                const float* __restrict__ Wsrc,
                                                const int* __restrict__ dtype,
                                                __hip_bfloat16* __restrict__ WdT) {
    int id = blockIdx.x * 256 + threadIdx.x;   // [0, ODIM*HDIM)
    int n = id >> 10;                          // 0..255
    int k = id & 1023;                         // 0..1023
    const float* W = (*dtype == 0) ? Wself : Wsrc;
    WdT[id] = __float2bfloat16(W[(size_t)k * ODIM + n]);
}

// ---------------------------------------------------------------------------
// K1: encoder GEMM fp32.  H = X[M,256] * W_enc[256,1024] + b_enc
// BM=128 BN=128 BK=32, 256 threads, 8x8 micro-tile (two float4 col groups).
// ---------------------------------------------------------------------------
__global__ __launch_bounds__(256) void k1_enc(const float* __restrict__ X,
                                              const float* __restrict__ W,
                                              const float* __restrict__ bias,
                                              float* __restrict__ H) {
    __shared__ __align__(16) float As[32][132];   // [k][m], +4 pad
    __shared__ __align__(16) float Bs[32][128];   // [k][n]
    const int t  = threadIdx.x;
    const int m0 = blockIdx.x * 128;
    const int n0 = blockIdx.y * 128;
    const int tx = t & 15;
    const int ty = t >> 4;

    float acc[8][8];
#pragma unroll
    for (int i = 0; i < 8; ++i)
#pragma unroll
        for (int j = 0; j < 8; ++j) acc[i][j] = 0.0f;

    for (int kk = 0; kk < IDIM; kk += 32) {
        // A tile 128x32 (transpose into LDS)
#pragma unroll
        for (int r = 0; r < 4; ++r) {
            int idx = t + r * 256;            // 0..1023
            int row = idx >> 3;               // 0..127
            int k4  = (idx & 7) << 2;         // 0,4,...,28
            float4 a = *(const float4*)(X + (size_t)(m0 + row) * IDIM + kk + k4);
            As[k4 + 0][row] = a.x;
            As[k4 + 1][row] = a.y;
            As[k4 + 2][row] = a.z;
            As[k4 + 3][row] = a.w;
        }
        // B tile 32x128
#pragma unroll
        for (int r = 0; r < 4; ++r) {
            int idx = t + r * 256;
            int row = idx >> 5;               // 0..31
            int c4  = (idx & 31) << 2;        // 0..124
            *(float4*)&Bs[row][c4] =
                *(const float4*)(W + (size_t)(kk + row) * HDIM + n0 + c4);
        }
        __syncthreads();

#pragma unroll 8
        for (int k = 0; k < 32; ++k) {
            float4 a0 = *(const float4*)&As[k][ty * 8];
            float4 a1 = *(const float4*)&As[k][ty * 8 + 4];
            float4 b0 = *(const float4*)&Bs[k][tx * 4];         // col group 0
            float4 b1 = *(const float4*)&Bs[k][tx * 4 + 64];    // col group 1
            float av[8] = {a0.x, a0.y, a0.z, a0.w, a1.x, a1.y, a1.z, a1.w};
            float bv[8] = {b0.x, b0.y, b0.z, b0.w, b1.x, b1.y, b1.z, b1.w};
#pragma unroll
            for (int i = 0; i < 8; ++i)
#pragma unroll
                for (int j = 0; j < 8; ++j)
                    acc[i][j] = fmaf(av[i], bv[j], acc[i][j]);
        }
        __syncthreads();
    }

    // epilogue + bias; cols: group0 = n0+tx*4, group1 = n0+64+tx*4
#pragma unroll
    for (int i = 0; i < 8; ++i) {
        int gm = m0 + ty * 8 + i;
        float* o = H + (size_t)gm * HDIM + n0;
        float4 v0, v1;
        v0.x = acc[i][0] + bias[n0 + tx * 4 + 0];
        v0.y = acc[i][1] + bias[n0 + tx * 4 + 1];
        v0.z = acc[i][2] + bias[n0 + tx * 4 + 2];
        v0.w = acc[i][3] + bias[n0 + tx * 4 + 3];
        v1.x = acc[i][4] + bias[n0 + 64 + tx * 4 + 0];
        v1.y = acc[i][5] + bias[n0 + 64 + tx * 4 + 1];
        v1.z = acc[i][6] + bias[n0 + 64 + tx * 4 + 2];
        v1.w = acc[i][7] + bias[n0 + 64 + tx * 4 + 3];
        *(float4*)(o + tx * 4) = v0;
        *(float4*)(o + 64 + tx * 4) = v1;
    }
}

// ---------------------------------------------------------------------------
// K2: per-row (one wave per row) radix-select top-128 / top-256 by energy,
// write mask_new in place over h, write masked bf16 h to ws.
// ---------------------------------------------------------------------------
__device__ __forceinline__ unsigned int radix_kth(const unsigned int* u, int k,
                                                  unsigned int* hist,
                                                  unsigned int* res,
                                                  int lane, int* r_out) {
    unsigned int prefix = 0;
    int kk = k;
    for (int pass = 3; pass >= 0; --pass) {
        const int sh = pass * 8;
        hist[lane] = 0u; hist[lane + 64] = 0u;
        hist[lane + 128] = 0u; hist[lane + 192] = 0u;
        __syncthreads();
#pragma unroll
        for (int i = 0; i < 16; ++i) {
            bool matched = (pass == 3) || ((u[i] >> (sh + 8)) == (prefix >> (sh + 8)));
            if (matched) atomicAdd(&hist[(u[i] >> sh) & 0xFFu], 1u);
        }
        __syncthreads();
        unsigned int c0 = hist[lane * 4 + 0], c1 = hist[lane * 4 + 1];
        unsigned int c2 = hist[lane * 4 + 2], c3 = hist[lane * 4 + 3];
        unsigned int lt = c0 + c1 + c2 + c3;
        // suffix-sum over lanes: s = sum of lt for lanes >= me
        unsigned int s = lt;
#pragma unroll
        for (int off = 1; off < 64; off <<= 1) {
            unsigned int o = (unsigned int)__shfl_down((int)s, off, 64);
            if (lane + off < 64) s += o;
        }
        unsigned int gt_lanes = s - lt;
        unsigned int cs[4] = {c0, c1, c2, c3};
        unsigned int sf[4] = {c1 + c2 + c3, c2 + c3, c3, 0u};
#pragma unroll
        for (int q = 0; q < 4; ++q) {
            int gt = (int)(gt_lanes + sf[q]);
            int ge = gt + (int)cs[q];
            if (gt < kk && kk <= ge) {           // exactly one (lane,q) matches
                res[0] = (unsigned int)(lane * 4 + q);
                res[1] = (unsigned int)gt;
            }
        }
        __syncthreads();
        unsigned int b = res[0];
        kk -= (int)res[1];
        prefix |= (b << sh);
        __syncthreads();
    }
    *r_out = kk;   // how many to take among values == prefix (tie slots)
    return prefix;
}

__global__ __launch_bounds__(256) void k2_topk(const float* __restrict__ mask_prev,
                                               float* __restrict__ Hio,
                                               __hip_bfloat16* __restrict__ Abf) {
    __shared__ unsigned int hist[4][256];
    __shared__ unsigned int res[4][2];
    const int t = threadIdx.x;
    const int wave = t >> 6;
    const int lane = t & 63;
    const size_t row = (size_t)blockIdx.x * 4 + wave;
    const float* mp = mask_prev + row * HDIM;
    float* hrow = Hio + row * HDIM;

    float hv[16], mpv[16];
    unsigned int u[16];
#pragma unroll
    for (int i = 0; i < 16; ++i) {
        int j = lane + (i << 6);               // index order = (i asc, lane asc)
        float m = mp[j];
        float h = hrow[j];
        h = (m > 0.0f) ? 0.0f : h;             // hidden_exclude_activation
        mpv[i] = m; hv[i] = h;
        float e = h * h;
        u[i] = __float_as_uint(e);             // non-neg float: uint-monotone
    }

    int r1, r2;
    unsigned int T1 = radix_kth(u, CDIM,     hist[wave], res[wave], lane, &r1);
    unsigned int T2 = radix_kth(u, 2 * CDIM, hist[wave], res[wave], lane, &r2);

    const unsigned long long below = (1ULL << lane) - 1ULL;
    int c1 = 0, c2 = 0;
#pragma unroll
    for (int i = 0; i < 16; ++i) {
        unsigned long long b1 = __ballot(u[i] == T1);
        unsigned long long b2 = __ballot(u[i] == T2);
        bool s1 = (u[i] > T1) || ((u[i] == T1) && (c1 + __popcll(b1 & below) < r1));
        bool s2 = (u[i] > T2) || ((u[i] == T2) && (c2 + __popcll(b2 & below) < r2));
        c1 += __popcll(b1);
        c2 += __popcll(b2);
        int j = lane + (i << 6);
        hrow[j] = mpv[i] + (s1 ? 1.0f : 0.0f);            // mask_new, in place
        Abf[row * HDIM + j] = __float2bfloat16(s2 ? hv[i] : 0.0f);
    }
}

// ---------------------------------------------------------------------------
// K3: decoder GEMM bf16 MFMA.  Out = A[M,1024](bf16) * WdT^T + b_dec
// 128x128 tile, BK=32, 4 waves, 4x4 fragments of 16x16x32 per wave.
// ---------------------------------------------------------------------------
__global__ __launch_bounds__(256) void k3_dec(const __hip_bfloat16* __restrict__ A,
                                              const __hip_bfloat16* __restrict__ Bt,
                                              const float* __restrict__ bias_self,
                                              const float* __restrict__ bias_src,
                                              const int* __restrict__ dtype,
                                              float* __restrict__ Out) {
    __shared__ __align__(16) __hip_bfloat16 As[128 * 32];   // [m][k]
    __shared__ __align__(16) __hip_bfloat16 Bs[128 * 32];   // [n][k]
    const int t = threadIdx.x;
    const int lane = t & 63;
    const int wave = t >> 6;
    const int m0 = blockIdx.x * 128;
    const int n0 = blockIdx.y * 128;
    const int wr = wave >> 1;
    const int wc = wave & 1;
    const int quad = lane >> 4;
    const int rf = lane & 15;

    floatx4 acc[4][4];
    const floatx4 z = {0.0f, 0.0f, 0.0f, 0.0f};
#pragma unroll
    for (int i = 0; i < 4; ++i)
#pragma unroll
        for (int j = 0; j < 4; ++j) acc[i][j] = z;

    for (int kk = 0; kk < HDIM; kk += 32) {
#pragma unroll
        for (int p = 0; p < 2; ++p) {
            int l = p * 256 + t;                 // 0..511
            int row = l >> 2;                    // 0..127
            int kc = (l & 3) << 3;               // bf16 elems: 0,8,16,24
            *(uint4*)&As[row * 32 + kc] =
                *(const uint4*)(A + (size_t)(m0 + row) * HDIM + kk + kc);
            *(uint4*)&Bs[row * 32 + kc] =
                *(const uint4*)(Bt + (size_t)(n0 + row) * HDIM + kk + kc);
        }
        __syncthreads();

        shortx8 af[4], bf[4];
#pragma unroll
        for (int i = 0; i < 4; ++i) {
            af[i] = *(const shortx8*)&As[(wr * 64 + i * 16 + rf) * 32 + quad * 8];
            bf[i] = *(const shortx8*)&Bs[(wc * 64 + i * 16 + rf) * 32 + quad * 8];
        }
#pragma unroll
        for (int mi = 0; mi < 4; ++mi)
#pragma unroll
            for (int nj = 0; nj < 4; ++nj)
                acc[mi][nj] = __builtin_amdgcn_mfma_f32_16x16x32_bf16(
                    af[mi], bf[nj], acc[mi][nj], 0, 0, 0);
        __syncthreads();
    }

    const float* bias = (*dtype == 0) ? bias_self : bias_src;
#pragma unroll
    for (int mi = 0; mi < 4; ++mi) {
#pragma unroll
        for (int nj = 0; nj < 4; ++nj) {
            int gn = n0 + wc * 64 + nj * 16 + rf;           // C/D: col = lane&15
            float bv = bias[gn];
            int gmb = m0 + wr * 64 + mi * 16 + quad * 4;    // row = quad*4 + reg
#pragma unroll
            for (int r2 = 0; r2 < 4; ++r2)
                Out[(size_t)(gmb + r2) * ODIM + gn] = acc[mi][nj][r2] + bv;
        }
    }
}

// ---------------------------------------------------------------------------
extern "C" void kernel_launch(void* const* d_in, const int* in_sizes, int n_in,
                              void* d_out, int out_size, void* d_ws, size_t ws_size,
                              hipStream_t stream) {
    const float* x          = (const float*)d_in[0];
    const float* mask_prev  = (const float*)d_in[1];
    const float* W_enc      = (const float*)d_in[2];
    const float* b_enc      = (const float*)d_in[3];
    const float* W_dec_self = (const float*)d_in[4];
    const float* b_dec_self = (const float*)d_in[5];
    const float* W_dec_src  = (const float*)d_in[6];
    const float* b_dec_src  = (const float*)d_in[7];
    const int*   dtype      = (const int*)d_in[8];

    float* out  = (float*)d_out;
    float* Hbuf = out + OUT_OFF;   // h staged in mask_new output region (in-place per row)

    __hip_bfloat16* Abf = (__hip_bfloat16*)d_ws;                             // 128 MB
    __hip_bfloat16* WdT = (__hip_bfloat16*)((char*)d_ws + (size_t)M_ * HDIM * 2);

    k0_convw<<<dim3((ODIM * HDIM) / 256), 256, 0, stream>>>(W_dec_self, W_dec_src, dtype, WdT);
    k1_enc  <<<dim3(M_ / 128, HDIM / 128), 256, 0, stream>>>(x, W_enc, b_enc, Hbuf);
    k2_topk <<<dim3(M_ / 4), 256, 0, stream>>>(mask_prev, Hbuf, Abf);
    k3_dec  <<<dim3(M_ / 128, ODIM / 128), 256, 0, stream>>>(Abf, WdT, b_dec_self, b_dec_src, dtype, out);
}